// Round 3
// baseline (262.103 us; speedup 1.0000x reference)
//
#include <hip/hip_runtime.h>

// SFM recurrent model: B=2048, T=60, D=6, H=64, F=10, O=1.
// Layout: 1024 blocks x 128 threads (2 waves). Block handles 2 batches.
// wave 0: gates (i, ste) for both batches; owns batch 0 state/pointwise.
// wave 1: gates (c, o)  for both batches; owns batch 1 state/pointwise.
// Lane = h index (0..63). U matrices live in VGPRs (64+64 per wave).
//
// R1: launch_bounds(128,2) -> compiler chased occupancy, 124 VGPR, U
//     rematerialized from cache every step -> 182 us.
// R2: waves_per_eu(2,2) raised the BUDGET to 256 but allocator still
//     chose 124 (remat is legal on const memory) -> unchanged.
// R3: asm volatile "+v" pins after the one-time load make the values
//     opaque redefinitions -> remat illegal -> U stays resident.

#define BB 2048
#define TT 60
#define DD 6
#define HH 64
#define FF 10

__device__ __forceinline__ float hsig_f(float v) {
    return fminf(fmaxf(fmaf(v, 0.16666666666666666f, 0.5f), 0.0f), 1.0f);
}

__device__ __forceinline__ float tanh_f(float x) {
    float xc = fminf(fmaxf(x, -12.0f), 12.0f);
    float e  = __builtin_amdgcn_exp2f(xc * 2.8853900817779268f); // 2*log2(e)
    return (e - 1.0f) * __builtin_amdgcn_rcpf(e + 1.0f);
}

__device__ __forceinline__ float rdlane(float v, int l) {
    return __int_as_float(__builtin_amdgcn_readlane(__float_as_int(v), l));
}

__device__ __forceinline__ float uni(float v) {
    return __int_as_float(__builtin_amdgcn_readfirstlane(__float_as_int(v)));
}

__device__ __forceinline__ void pin(float& v) {
    asm volatile("" : "+v"(v));
}

__global__ __launch_bounds__(128)
__attribute__((amdgpu_waves_per_eu(2, 2)))
void sfm_kernel(
    const float* __restrict__ x,
    const float* __restrict__ W_i,  const float* __restrict__ U_i,  const float* __restrict__ b_i,
    const float* __restrict__ W_ste,const float* __restrict__ U_ste,const float* __restrict__ b_ste,
    const float* __restrict__ W_fre,const float* __restrict__ U_fre,const float* __restrict__ b_fre,
    const float* __restrict__ W_c,  const float* __restrict__ U_c,  const float* __restrict__ b_c,
    const float* __restrict__ W_o,  const float* __restrict__ U_o,  const float* __restrict__ b_o,
    const float* __restrict__ U_a,  const float* __restrict__ b_a,
    const float* __restrict__ W_p,  const float* __restrict__ b_p,
    float* __restrict__ out)
{
    const int tid  = threadIdx.x;
    const int lane = tid & 63;
    const int wave = tid >> 6;   // 0 or 1
    const int b0   = blockIdx.x * 2;

    __shared__ float h_s[2][HH];    // current h per batch
    __shared__ float zx[4][HH];     // [0]=i(b1) [1]=ste(b1) [2]=c(b0) [3]=o(b0)
    __shared__ float fp_s[2][64];   // fre partial sums
    __shared__ float fre_s[2][16];  // activated fre per batch
    __shared__ float x_s[2 * TT * DD]; // staged x for both batches (720 floats)

    // ---- stage x into LDS (coalesced, once) ----
    {
        const float* xb = x + (size_t)b0 * TT * DD;
        #pragma unroll
        for (int i = tid; i < 2 * TT * DD; i += 128) x_s[i] = xb[i];
    }

    // ---- per-wave gate weights into registers ----
    const float* Wa = (wave == 0) ? W_i   : W_c;
    const float* Ua = (wave == 0) ? U_i   : U_c;
    const float* ba = (wave == 0) ? b_i   : b_c;
    const float* Wb = (wave == 0) ? W_ste : W_o;
    const float* Ub = (wave == 0) ? U_ste : U_o;
    const float* bb = (wave == 0) ? b_ste : b_o;

    float uA[HH], uB[HH];
    #pragma unroll
    for (int j = 0; j < HH; ++j) { uA[j] = Ua[j * HH + lane]; uB[j] = Ub[j * HH + lane]; }
    float wA[DD], wB[DD];
    #pragma unroll
    for (int d = 0; d < DD; ++d) { wA[d] = Wa[d * HH + lane]; wB[d] = Wb[d * HH + lane]; }

    // Force residency: opaque redefinition -> no remat inside the loop.
    #pragma unroll
    for (int j = 0; j < HH; ++j) { pin(uA[j]); pin(uB[j]); }
    #pragma unroll
    for (int d = 0; d < DD; ++d) { pin(wA[d]); pin(wB[d]); }

    const float bAv = ba[lane];
    const float bBv = bb[lane];
    const float bav = b_a[lane];
    const float wpv = W_p[lane];
    const float bpv = uni(b_p[0]);

    // U_a column -> SGPRs (uniform)
    float uav[FF];
    #pragma unroll
    for (int f = 0; f < FF; ++f) uav[f] = uni(U_a[f]);

    // ---- fre partial-sum lane mapping: lane = f*6 + jc (lanes 0..59) ----
    const int  f_idx = lane / 6;
    const int  jc    = lane - f_idx * 6;
    const bool fre_active = (lane < 60);
    const int  j0   = jc * 11 - ((jc > 4) ? 1 : 0);   // chunks 11,11,11,11,10,10
    const int  jlen = (jc < 4) ? 11 : 10;
    float ufre[11];
    #pragma unroll
    for (int i = 0; i < 11; ++i)
        ufre[i] = (fre_active && i < jlen) ? U_fre[(j0 + i) * FF + f_idx] : 0.0f;
    #pragma unroll
    for (int i = 0; i < 11; ++i) pin(ufre[i]);

    float wfre[DD];
    float bfre = 0.0f;
    #pragma unroll
    for (int d = 0; d < DD; ++d) wfre[d] = 0.0f;
    if (lane < FF) {
        #pragma unroll
        for (int d = 0; d < DD; ++d) wfre[d] = W_fre[d * FF + lane];
        bfre = b_fre[lane];
    }
    #pragma unroll
    for (int d = 0; d < DD; ++d) pin(wfre[d]);

    // ---- rotation constants: cos/sin(2*pi*f/10), exact ----
    const float CB[FF] = { 1.0f,  0.8090169943749475f,  0.30901699437494745f,
                          -0.30901699437494745f, -0.8090169943749475f, -1.0f,
                          -0.8090169943749475f, -0.30901699437494745f,
                           0.30901699437494745f,  0.8090169943749475f };
    const float SB[FF] = { 0.0f,  0.5877852522924731f,  0.9510565162951535f,
                           0.9510565162951535f,  0.5877852522924731f,  0.0f,
                          -0.5877852522924731f, -0.9510565162951535f,
                          -0.9510565162951535f, -0.5877852522924731f };

    // ---- state ----
    float Sre[FF], Sim[FF], cs[FF], sn[FF];
    #pragma unroll
    for (int f = 0; f < FF; ++f) { Sre[f] = 0.0f; Sim[f] = 0.0f; cs[f] = CB[f]; sn[f] = SB[f]; }
    float hself = 0.0f;

    h_s[wave][lane] = 0.0f;

    int sm = 0; // step mod 10
    for (int s = 0; s < TT; ++s) {
        __syncthreads();   // barrier 1: h_s (and zx reuse) coherent

        // ---- phase A: gate pre-activations ----
        float xs0[DD], xs1[DD];
        #pragma unroll
        for (int d = 0; d < DD; ++d) {
            xs0[d] = uni(x_s[s * DD + d]);
            xs1[d] = uni(x_s[TT * DD + s * DD + d]);
        }

        float hreg0 = h_s[0][lane];
        float hreg1 = h_s[1][lane];

        float zA0 = bAv, zB0 = bBv, zA1 = bAv, zB1 = bBv;
        #pragma unroll
        for (int d = 0; d < DD; ++d) {
            zA0 = fmaf(xs0[d], wA[d], zA0);
            zB0 = fmaf(xs0[d], wB[d], zB0);
            zA1 = fmaf(xs1[d], wA[d], zA1);
            zB1 = fmaf(xs1[d], wB[d], zB1);
        }
        #pragma unroll
        for (int j = 0; j < HH; ++j) {
            float h0 = rdlane(hreg0, j);
            float h1 = rdlane(hreg1, j);
            zA0 = fmaf(h0, uA[j], zA0);
            zB0 = fmaf(h0, uB[j], zB0);
            zA1 = fmaf(h1, uA[j], zA1);
            zB1 = fmaf(h1, uB[j], zB1);
        }

        if (wave == 0) { zx[0][lane] = zA1; zx[1][lane] = zB1; }
        else           { zx[2][lane] = zA0; zx[3][lane] = zB0; }

        // ---- fre for own batch (intra-wave) ----
        float part = 0.0f;
        #pragma unroll
        for (int i = 0; i < 11; ++i) {
            int jj = j0 + i; jj = (jj > 63) ? 63 : jj;
            part = fmaf(h_s[wave][jj], ufre[i], part);
        }
        fp_s[wave][lane] = part;
        if (lane < FF) {
            float acc = bfre;
            #pragma unroll
            for (int q = 0; q < 6; ++q) acc += fp_s[wave][lane * 6 + q];
            #pragma unroll
            for (int d = 0; d < DD; ++d)
                acc = fmaf((wave == 0) ? xs0[d] : xs1[d], wfre[d], acc);
            fre_s[wave][lane] = hsig_f(acc);
        }

        __syncthreads();   // barrier 2: zx coherent

        // ---- phase B: pointwise update for own batch ----
        float zi, zst, zc, zo;
        if (wave == 0) { zi = zA0;        zst = zB0;        zc = zx[2][lane]; zo = zx[3][lane]; }
        else           { zi = zx[0][lane]; zst = zx[1][lane]; zc = zA1;       zo = zB1; }

        float iv  = hsig_f(zi);
        float stv = hsig_f(zst);
        float ov  = hsig_f(zo);
        float cv  = iv * tanh_f(zc);

        if (sm == 0) {
            #pragma unroll
            for (int f = 0; f < FF; ++f) { cs[f] = CB[f]; sn[f] = SB[f]; }
        }

        float aacc = bav;
        #pragma unroll
        for (int f = 0; f < FF; ++f) {
            float frf = fre_s[wave][f];
            float fc  = stv * frf;
            Sre[f] = fmaf(cv, cs[f], fc * Sre[f]);
            Sim[f] = fmaf(cv, sn[f], fc * Sim[f]);
            float A = fmaf(Sim[f], Sim[f], Sre[f] * Sre[f]);
            aacc = fmaf(A, uav[f], aacc);
        }
        float av = tanh_f(aacc);
        hself = ov * av;
        h_s[wave][lane] = hself;

        // rotate (cs,sn) by 2*pi*f/10 for next step
        #pragma unroll
        for (int f = 0; f < FF; ++f) {
            float c0 = cs[f];
            cs[f] = fmaf(c0, CB[f], -(sn[f] * SB[f]));
            sn[f] = fmaf(c0, SB[f],   sn[f] * CB[f]);
        }
        if (++sm == 10) sm = 0;
    }

    // ---- output: out[b] = sum_k h[k]*W_p[k] + b_p ----
    float val = hself * wpv;
    #pragma unroll
    for (int off = 32; off > 0; off >>= 1) val += __shfl_xor(val, off, 64);
    if (lane == 0) out[b0 + wave] = val + bpv;
}

extern "C" void kernel_launch(void* const* d_in, const int* in_sizes, int n_in,
                              void* d_out, int out_size, void* d_ws, size_t ws_size,
                              hipStream_t stream) {
    (void)in_sizes; (void)n_in; (void)d_ws; (void)ws_size; (void)out_size;
    const float* x     = (const float*)d_in[0];
    const float* W_i   = (const float*)d_in[1];
    const float* U_i   = (const float*)d_in[2];
    const float* b_i   = (const float*)d_in[3];
    const float* W_ste = (const float*)d_in[4];
    const float* U_ste = (const float*)d_in[5];
    const float* b_ste = (const float*)d_in[6];
    const float* W_fre = (const float*)d_in[7];
    const float* U_fre = (const float*)d_in[8];
    const float* b_fre = (const float*)d_in[9];
    const float* W_c   = (const float*)d_in[10];
    const float* U_c   = (const float*)d_in[11];
    const float* b_c   = (const float*)d_in[12];
    const float* W_o   = (const float*)d_in[13];
    const float* U_o   = (const float*)d_in[14];
    const float* b_o   = (const float*)d_in[15];
    const float* U_a   = (const float*)d_in[16];
    const float* b_a   = (const float*)d_in[17];
    const float* W_p   = (const float*)d_in[18];
    const float* b_p   = (const float*)d_in[19];

    sfm_kernel<<<BB / 2, 128, 0, stream>>>(
        x, W_i, U_i, b_i, W_ste, U_ste, b_ste, W_fre, U_fre, b_fre,
        W_c, U_c, b_c, W_o, U_o, b_o, U_a, b_a, W_p, b_p, (float*)d_out);
}

// Round 4
// 182.013 us; speedup vs baseline: 1.4400x; 1.4400x over previous
//
#include <hip/hip_runtime.h>

// SFM recurrent model via MFMA: B=2048, T=60, D=6, H=64, F=10, O=1.
//
// R1-R3 (VALU readlane-GEMV): stuck at 183 us, VALUBusy 68%. Implied
// dynamic VALU ~1260 inst/step/wave vs ~610 hand-counted -> readlane
// (lane crossbar) is ~1/4-rate. Broadcast-free GEMV == matrix pipe.
//
// R4: all 5 GEMVs (i,ste,c,o gates + fre) via mfma_f32_16x16x32_bf16,
// split-bf16 (hi+lo, 3 products, lo*lo dropped ~2^-17). x@W and biases
// folded into the MFMA with extended K: rows 0..63 = h@U, 64..69 = x@W,
// 70 = 1.0*bias. 256 blocks x 256 thr (1 blk/CU, 1 wave/SIMD),
// 8 batches/block; wave g owns gate g (B-frags static in regs),
// wave 3 additionally owns the fre tile (n=0..9 valid).
// C layout: n=lane&15 (hcol), m=quad*4+reg (batch; quads 0,1 valid).

#define BB 2048
#define TT 60
#define DD 6
#define HH 64
#define FF 10

typedef short bf16x8 __attribute__((ext_vector_type(8)));
typedef float f32x4  __attribute__((ext_vector_type(4)));

__device__ __forceinline__ unsigned short f2bf(float f) {
    union { float f; unsigned u; } v; v.f = f;
    unsigned r = v.u + 0x7fffu + ((v.u >> 16) & 1u);   // round-to-nearest-even
    return (unsigned short)(r >> 16);
}
__device__ __forceinline__ float bf2f(unsigned short b) {
    union { unsigned u; float f; } v; v.u = ((unsigned)b) << 16; return v.f;
}

__device__ __forceinline__ float hsig_f(float v) {
    return fminf(fmaxf(fmaf(v, 0.16666666666666666f, 0.5f), 0.0f), 1.0f);
}
__device__ __forceinline__ float tanh_f(float x) {
    float xc = fminf(fmaxf(x, -12.0f), 12.0f);
    float e  = __builtin_amdgcn_exp2f(xc * 2.8853900817779268f); // 2*log2(e)
    return (e - 1.0f) * __builtin_amdgcn_rcpf(e + 1.0f);
}
__device__ __forceinline__ float uni(float v) {
    return __int_as_float(__builtin_amdgcn_readfirstlane(__float_as_int(v)));
}
__device__ __forceinline__ void pinv(bf16x8& v) { asm volatile("" : "+v"(v)); }

__global__ __launch_bounds__(256)
__attribute__((amdgpu_waves_per_eu(1, 1)))
void sfm_kernel(
    const float* __restrict__ x,
    const float* __restrict__ W_i,  const float* __restrict__ U_i,  const float* __restrict__ b_i,
    const float* __restrict__ W_ste,const float* __restrict__ U_ste,const float* __restrict__ b_ste,
    const float* __restrict__ W_fre,const float* __restrict__ U_fre,const float* __restrict__ b_fre,
    const float* __restrict__ W_c,  const float* __restrict__ U_c,  const float* __restrict__ b_c,
    const float* __restrict__ W_o,  const float* __restrict__ U_o,  const float* __restrict__ b_o,
    const float* __restrict__ U_a,  const float* __restrict__ b_a,
    const float* __restrict__ W_p,  const float* __restrict__ b_p,
    float* __restrict__ out)
{
    const int tid  = threadIdx.x;
    const int lane = tid & 63;
    const int wave = tid >> 6;      // == gate id (0=i,1=ste,2=c,3=o)
    const int q    = lane >> 4;     // quad 0..3
    const int n16  = lane & 15;
    const int b0   = blockIdx.x * 8;

    __shared__ __align__(16) float xbuf[8 * TT * DD];  // 2880: x[b][t][d]
    __shared__ __align__(16) float hbuf[8 * 68];       // 544: h[b][hcol], pad 68
    __shared__ __align__(16) float zbuf[4 * 64 * 12];  // 3072: z[g][hcol][b pad12]
    __shared__ __align__(16) float frebuf[16 * 12];    // 192: zfre[f][b pad12]

    // ---- stage x (coalesced float4) + zero h ----
    {
        const float4* xg = (const float4*)(x + (size_t)b0 * TT * DD);
        float4* xs = (float4*)xbuf;
        for (int i = tid; i < (8 * TT * DD) / 4; i += 256) xs[i] = xg[i];
    }
    for (int i = tid; i < 8 * 68; i += 256) hbuf[i] = 0.0f;

    // ---- per-wave gate weights ----
    const float* Ug = (wave == 0) ? U_i : (wave == 1) ? U_ste : (wave == 2) ? U_c : U_o;
    const float* Wg = (wave == 0) ? W_i : (wave == 1) ? W_ste : (wave == 2) ? W_c : W_o;
    const float* bg = (wave == 0) ? b_i : (wave == 1) ? b_ste : (wave == 2) ? b_c : b_o;

    // ---- static B-frags: B[k][n], lane holds k = c*32 + q*8 + j, n = n16(+16t) ----
    bf16x8 Bh[5][3], Bl[5][3];
    #pragma unroll
    for (int t = 0; t < 5; ++t) {
        #pragma unroll
        for (int c = 0; c < 3; ++c) {
            #pragma unroll
            for (int j = 0; j < 8; ++j) {
                const int kv = c * 32 + q * 8 + j;   // 0..95 (71..95 zero rows)
                float v = 0.0f;
                if (t < 4) {
                    const int n = t * 16 + n16;
                    if      (kv < 64) v = Ug[kv * HH + n];
                    else if (kv < 70) v = Wg[(kv - 64) * HH + n];
                    else if (kv == 70) v = bg[n];
                } else if (wave == 3 && n16 < FF) {
                    if      (kv < 64) v = U_fre[kv * FF + n16];
                    else if (kv < 70) v = W_fre[(kv - 64) * FF + n16];
                    else if (kv == 70) v = b_fre[n16];
                }
                const unsigned short hb = f2bf(v);
                const float lo = v - bf2f(hb);
                Bh[t][c][j] = (short)hb;
                Bl[t][c][j] = (short)f2bf(lo);
            }
            pinv(Bh[t][c]); pinv(Bl[t][c]);
        }
    }

    // ---- pointwise thread mapping: batch pb, hcols {pp, pp+32} ----
    const int pb = tid >> 5;
    const int pp = tid & 31;
    const float ba0 = b_a[pp], ba1 = b_a[pp + 32];
    const float wp0 = W_p[pp], wp1 = W_p[pp + 32];
    const float bpv = uni(b_p[0]);
    float uav[FF];
    #pragma unroll
    for (int f = 0; f < FF; ++f) uav[f] = uni(U_a[f]);

    // ---- rotation constants: cos/sin(2*pi*f/10), exact, period-10 reset ----
    const float CBt[FF] = { 1.0f,  0.8090169943749475f,  0.30901699437494745f,
                           -0.30901699437494745f, -0.8090169943749475f, -1.0f,
                           -0.8090169943749475f, -0.30901699437494745f,
                            0.30901699437494745f,  0.8090169943749475f };
    const float SBt[FF] = { 0.0f,  0.5877852522924731f,  0.9510565162951535f,
                            0.9510565162951535f,  0.5877852522924731f,  0.0f,
                           -0.5877852522924731f, -0.9510565162951535f,
                           -0.9510565162951535f, -0.5877852522924731f };

    float Sre0[FF], Sim0[FF], Sre1[FF], Sim1[FF], cs[FF], sn[FF];
    #pragma unroll
    for (int f = 0; f < FF; ++f) {
        Sre0[f] = 0.0f; Sim0[f] = 0.0f; Sre1[f] = 0.0f; Sim1[f] = 0.0f;
        cs[f] = CBt[f]; sn[f] = SBt[f];
    }
    float h0v = 0.0f, h1v = 0.0f;

    __syncthreads();

    int sm = 0;
    for (int s = 0; s < TT; ++s) {
        // ---- A-frags: A[m][k], m = n16 (batch, &7 mirrored), k = c*32+q*8+j ----
        bf16x8 Ah[3], Al[3];
        {
            const int ab = n16 & 7;
            #pragma unroll
            for (int c = 0; c < 2; ++c) {
                const float* hp = &hbuf[ab * 68 + c * 32 + q * 8];
                const float4 v0 = *(const float4*)hp;
                const float4 v1 = *(const float4*)(hp + 4);
                const float tv[8] = {v0.x, v0.y, v0.z, v0.w, v1.x, v1.y, v1.z, v1.w};
                #pragma unroll
                for (int j = 0; j < 8; ++j) {
                    const unsigned short hb = f2bf(tv[j]);
                    const float lo = tv[j] - bf2f(hb);
                    Ah[c][j] = (short)hb; Al[c][j] = (short)f2bf(lo);
                }
            }
            float tv[8] = {0, 0, 0, 0, 0, 0, 0, 0};
            if (q == 0) {   // k rows 64..70: x_t (6) then 1.0
                const float2* x2 = (const float2*)&xbuf[ab * (TT * DD) + s * DD];
                const float2 a = x2[0], b = x2[1], c2 = x2[2];
                tv[0] = a.x; tv[1] = a.y; tv[2] = b.x; tv[3] = b.y; tv[4] = c2.x; tv[5] = c2.y;
                tv[6] = 1.0f;
            }
            #pragma unroll
            for (int j = 0; j < 8; ++j) {
                const unsigned short hb = f2bf(tv[j]);
                const float lo = tv[j] - bf2f(hb);
                Ah[2][j] = (short)hb; Al[2][j] = (short)f2bf(lo);
            }
        }

        // ---- MFMAs: z = (Ah+Al)(Bh+Bl), 3-term split ----
        f32x4 acc[5];
        #pragma unroll
        for (int t = 0; t < 5; ++t) {
            if (t < 4 || wave == 3) {
                f32x4 a = {0.0f, 0.0f, 0.0f, 0.0f};
                #pragma unroll
                for (int c = 0; c < 3; ++c) {
                    a = __builtin_amdgcn_mfma_f32_16x16x32_bf16(Al[c], Bh[t][c], a, 0, 0, 0);
                    a = __builtin_amdgcn_mfma_f32_16x16x32_bf16(Ah[c], Bl[t][c], a, 0, 0, 0);
                    a = __builtin_amdgcn_mfma_f32_16x16x32_bf16(Ah[c], Bh[t][c], a, 0, 0, 0);
                }
                acc[t] = a;
            }
        }

        // ---- write z to LDS (quads 0,1 hold batches 0..7) ----
        if (lane < 32) {
            #pragma unroll
            for (int t = 0; t < 4; ++t)
                *(f32x4*)&zbuf[(wave * 64 + t * 16 + n16) * 12 + q * 4] = acc[t];
            if (wave == 3 && n16 < FF)
                *(f32x4*)&frebuf[n16 * 12 + q * 4] = acc[4];
        }
        __syncthreads();

        // ---- pointwise: batch pb, hcols pp & pp+32 ----
        const float zi0 = zbuf[(0 * 64 + pp) * 12 + pb], zi1 = zbuf[(0 * 64 + pp + 32) * 12 + pb];
        const float zs0 = zbuf[(1 * 64 + pp) * 12 + pb], zs1 = zbuf[(1 * 64 + pp + 32) * 12 + pb];
        const float zc0 = zbuf[(2 * 64 + pp) * 12 + pb], zc1 = zbuf[(2 * 64 + pp + 32) * 12 + pb];
        const float zo0 = zbuf[(3 * 64 + pp) * 12 + pb], zo1 = zbuf[(3 * 64 + pp + 32) * 12 + pb];
        float fr[FF];
        #pragma unroll
        for (int f = 0; f < FF; ++f) fr[f] = hsig_f(frebuf[f * 12 + pb]);

        const float i0 = hsig_f(zi0), st0 = hsig_f(zs0), o0 = hsig_f(zo0);
        const float i1 = hsig_f(zi1), st1 = hsig_f(zs1), o1 = hsig_f(zo1);
        const float c0 = i0 * tanh_f(zc0);
        const float c1 = i1 * tanh_f(zc1);

        if (sm == 0) {
            #pragma unroll
            for (int f = 0; f < FF; ++f) { cs[f] = CBt[f]; sn[f] = SBt[f]; }
        }

        float a0 = ba0, a1 = ba1;
        #pragma unroll
        for (int f = 0; f < FF; ++f) {
            const float fc0 = st0 * fr[f], fc1 = st1 * fr[f];
            Sre0[f] = fmaf(fc0, Sre0[f], c0 * cs[f]);
            Sim0[f] = fmaf(fc0, Sim0[f], c0 * sn[f]);
            Sre1[f] = fmaf(fc1, Sre1[f], c1 * cs[f]);
            Sim1[f] = fmaf(fc1, Sim1[f], c1 * sn[f]);
            const float A0 = fmaf(Sim0[f], Sim0[f], Sre0[f] * Sre0[f]);
            const float A1 = fmaf(Sim1[f], Sim1[f], Sre1[f] * Sre1[f]);
            a0 = fmaf(A0, uav[f], a0);
            a1 = fmaf(A1, uav[f], a1);
            const float cc = cs[f];
            cs[f] = fmaf(cc, CBt[f], -(sn[f] * SBt[f]));
            sn[f] = fmaf(cc, SBt[f],   sn[f] * CBt[f]);
        }
        h0v = o0 * tanh_f(a0);
        h1v = o1 * tanh_f(a1);
        hbuf[pb * 68 + pp]      = h0v;
        hbuf[pb * 68 + pp + 32] = h1v;
        if (++sm == 10) sm = 0;
        __syncthreads();
    }

    // ---- output: out[b] = sum_h h*W_p + b_p (reduce 32 threads of same pb) ----
    float val = fmaf(h0v, wp0, h1v * wp1);
    #pragma unroll
    for (int off = 16; off > 0; off >>= 1) val += __shfl_xor(val, off, 64);
    if (pp == 0) out[b0 + pb] = val + bpv;
}

extern "C" void kernel_launch(void* const* d_in, const int* in_sizes, int n_in,
                              void* d_out, int out_size, void* d_ws, size_t ws_size,
                              hipStream_t stream) {
    (void)in_sizes; (void)n_in; (void)d_ws; (void)ws_size; (void)out_size;
    const float* x     = (const float*)d_in[0];
    const float* W_i   = (const float*)d_in[1];
    const float* U_i   = (const float*)d_in[2];
    const float* b_i   = (const float*)d_in[3];
    const float* W_ste = (const float*)d_in[4];
    const float* U_ste = (const float*)d_in[5];
    const float* b_ste = (const float*)d_in[6];
    const float* W_fre = (const float*)d_in[7];
    const float* U_fre = (const float*)d_in[8];
    const float* b_fre = (const float*)d_in[9];
    const float* W_c   = (const float*)d_in[10];
    const float* U_c   = (const float*)d_in[11];
    const float* b_c   = (const float*)d_in[12];
    const float* W_o   = (const float*)d_in[13];
    const float* U_o   = (const float*)d_in[14];
    const float* b_o   = (const float*)d_in[15];
    const float* U_a   = (const float*)d_in[16];
    const float* b_a   = (const float*)d_in[17];
    const float* W_p   = (const float*)d_in[18];
    const float* b_p   = (const float*)d_in[19];

    sfm_kernel<<<BB / 8, 256, 0, stream>>>(
        x, W_i, U_i, b_i, W_ste, U_ste, b_ste, W_fre, U_fre, b_fre,
        W_c, U_c, b_c, W_o, U_o, b_o, U_a, b_a, W_p, b_p, (float*)d_out);
}

// Round 5
// 164.422 us; speedup vs baseline: 1.5941x; 1.1070x over previous
//
#include <hip/hip_runtime.h>

// SFM recurrent model via MFMA: B=2048, T=60, D=6, H=64, F=10, O=1.
//
// R1-R3: VALU readlane-GEMV stuck at 183 us (readlane ~1/4 rate).
// R4: 5 GEMVs via mfma_16x16x32_bf16 split-bf16 -> 100 us, MfmaUtil 15,
//     VALUBusy 41. ~830 instr/step/SIMD, of which ~240 = per-step fp32->
//     (hi,lo) bf16 conversion of A-frags + 4-way zbuf read conflicts.
// R5: pre-split h (at pointwise, once per value) and x (at staging) into
//     bf16 hi/lo stored in LDS; A-build = pure ds_read_b128. Pointwise
//     remapped (batch=tid&7, col=tid>>3) so zbuf reads are 2-way max.
//
// MFMA tile: m=batch(8 of 16), n=hcol, K=96: rows 0..63 h@U, 64..69 x@W,
// 70 bias (A row 70 = 1.0). Wave g owns gate g; wave 3 also fre tile.
// C layout: n=lane&15, m=quad*4+reg (quads 0,1 valid).

#define BB 2048
#define TT 60
#define DD 6
#define HH 64
#define FF 10

#define XS 968   // xsp per-batch stride in shorts (60*16 + 8 pad -> bank offset 4/row)
#define HS 72    // h split per-batch stride in shorts

typedef short bf16x8 __attribute__((ext_vector_type(8)));
typedef float f32x4  __attribute__((ext_vector_type(4)));

__device__ __forceinline__ unsigned short f2bf(float f) {
    union { float f; unsigned u; } v; v.f = f;
    unsigned r = v.u + 0x7fffu + ((v.u >> 16) & 1u);   // round-to-nearest-even
    return (unsigned short)(r >> 16);
}
__device__ __forceinline__ float bf2f(unsigned short b) {
    union { unsigned u; float f; } v; v.u = ((unsigned)b) << 16; return v.f;
}
__device__ __forceinline__ float hsig_f(float v) {
    return fminf(fmaxf(fmaf(v, 0.16666666666666666f, 0.5f), 0.0f), 1.0f);
}
__device__ __forceinline__ float tanh_f(float x) {
    float xc = fminf(fmaxf(x, -12.0f), 12.0f);
    float e  = __builtin_amdgcn_exp2f(xc * 2.8853900817779268f); // 2*log2(e)
    return (e - 1.0f) * __builtin_amdgcn_rcpf(e + 1.0f);
}
__device__ __forceinline__ float uni(float v) {
    return __int_as_float(__builtin_amdgcn_readfirstlane(__float_as_int(v)));
}
__device__ __forceinline__ void pinv(bf16x8& v) { asm volatile("" : "+v"(v)); }

__global__ __launch_bounds__(256)
__attribute__((amdgpu_waves_per_eu(1, 1)))
void sfm_kernel(
    const float* __restrict__ x,
    const float* __restrict__ W_i,  const float* __restrict__ U_i,  const float* __restrict__ b_i,
    const float* __restrict__ W_ste,const float* __restrict__ U_ste,const float* __restrict__ b_ste,
    const float* __restrict__ W_fre,const float* __restrict__ U_fre,const float* __restrict__ b_fre,
    const float* __restrict__ W_c,  const float* __restrict__ U_c,  const float* __restrict__ b_c,
    const float* __restrict__ W_o,  const float* __restrict__ U_o,  const float* __restrict__ b_o,
    const float* __restrict__ U_a,  const float* __restrict__ b_a,
    const float* __restrict__ W_p,  const float* __restrict__ b_p,
    float* __restrict__ out)
{
    const int tid  = threadIdx.x;
    const int lane = tid & 63;
    const int wave = tid >> 6;      // == gate id (0=i,1=ste,2=c,3=o)
    const int q    = lane >> 4;     // quad 0..3
    const int n16  = lane & 15;
    const int b0   = blockIdx.x * 8;

    __shared__ __align__(16) unsigned short xsp[8 * XS];   // presplit x: [b][s][hi0..5,1.0,0, lo0..5,0,0]
    __shared__ __align__(16) unsigned short hhi[8 * HS];   // h hi-bf16, padded rows
    __shared__ __align__(16) unsigned short hlo[8 * HS];   // h lo-bf16
    __shared__ __align__(16) float zbuf[4 * 64 * 12];      // z[g][hcol][b pad12]
    __shared__ __align__(16) float frebuf[16 * 12];        // zfre[f][b pad12]
    __shared__ float red[4][8];

    // ---- stage + pre-split x ----
    for (int item = tid; item < 8 * TT; item += 256) {
        const float* xg = x + (size_t)b0 * (TT * DD) + item * DD;
        const int b = item / TT, s = item - b * TT;
        unsigned short* dst = &xsp[b * XS + s * 16];
        #pragma unroll
        for (int d = 0; d < DD; ++d) {
            const float v = xg[d];
            const unsigned short hb = f2bf(v);
            dst[d]     = hb;
            dst[8 + d] = f2bf(v - bf2f(hb));
        }
        dst[6] = 0x3F80; dst[7] = 0;   // bias row: 1.0 exact, lo = 0
        dst[14] = 0; dst[15] = 0;
    }
    for (int i = tid; i < 8 * HS; i += 256) { hhi[i] = 0; hlo[i] = 0; }

    // ---- per-wave gate weights ----
    const float* Ug = (wave == 0) ? U_i : (wave == 1) ? U_ste : (wave == 2) ? U_c : U_o;
    const float* Wg = (wave == 0) ? W_i : (wave == 1) ? W_ste : (wave == 2) ? W_c : W_o;
    const float* bg = (wave == 0) ? b_i : (wave == 1) ? b_ste : (wave == 2) ? b_c : b_o;

    // ---- static B-frags: B[k][n], lane holds k = c*32 + q*8 + j, n = n16(+16t) ----
    bf16x8 Bh[5][3], Bl[5][3];
    #pragma unroll
    for (int t = 0; t < 5; ++t) {
        #pragma unroll
        for (int c = 0; c < 3; ++c) {
            #pragma unroll
            for (int j = 0; j < 8; ++j) {
                const int kv = c * 32 + q * 8 + j;   // 0..95 (71..95 zero rows)
                float v = 0.0f;
                if (t < 4) {
                    const int n = t * 16 + n16;
                    if      (kv < 64)  v = Ug[kv * HH + n];
                    else if (kv < 70)  v = Wg[(kv - 64) * HH + n];
                    else if (kv == 70) v = bg[n];
                } else if (wave == 3 && n16 < FF) {
                    if      (kv < 64)  v = U_fre[kv * FF + n16];
                    else if (kv < 70)  v = W_fre[(kv - 64) * FF + n16];
                    else if (kv == 70) v = b_fre[n16];
                }
                const unsigned short hb = f2bf(v);
                Bh[t][c][j] = (short)hb;
                Bl[t][c][j] = (short)f2bf(v - bf2f(hb));
            }
            pinv(Bh[t][c]); pinv(Bl[t][c]);
        }
    }

    // ---- pointwise mapping: batch pb = tid&7, cols {pc, pc+32}, pc = tid>>3 ----
    const int pb = tid & 7;
    const int pc = tid >> 3;
    const float ba0 = b_a[pc], ba1 = b_a[pc + 32];
    const float wp0 = W_p[pc], wp1 = W_p[pc + 32];
    const float bpv = uni(b_p[0]);
    float uav[FF];
    #pragma unroll
    for (int f = 0; f < FF; ++f) uav[f] = uni(U_a[f]);

    // ---- rotation constants: cos/sin(2*pi*f/10), exact, period-10 reset ----
    const float CBt[FF] = { 1.0f,  0.8090169943749475f,  0.30901699437494745f,
                           -0.30901699437494745f, -0.8090169943749475f, -1.0f,
                           -0.8090169943749475f, -0.30901699437494745f,
                            0.30901699437494745f,  0.8090169943749475f };
    const float SBt[FF] = { 0.0f,  0.5877852522924731f,  0.9510565162951535f,
                            0.9510565162951535f,  0.5877852522924731f,  0.0f,
                           -0.5877852522924731f, -0.9510565162951535f,
                           -0.9510565162951535f, -0.5877852522924731f };

    float Sre0[FF], Sim0[FF], Sre1[FF], Sim1[FF], cs[FF], sn[FF];
    #pragma unroll
    for (int f = 0; f < FF; ++f) {
        Sre0[f] = 0.0f; Sim0[f] = 0.0f; Sre1[f] = 0.0f; Sim1[f] = 0.0f;
        cs[f] = CBt[f]; sn[f] = SBt[f];
    }
    float h0v = 0.0f, h1v = 0.0f;

    __syncthreads();

    int sm = 0;
    for (int s = 0; s < TT; ++s) {
        // ---- A-frags: pure vector LDS reads of pre-split bf16 ----
        const int ab = n16 & 7;
        bf16x8 Ah[3], Al[3];
        #pragma unroll
        for (int c = 0; c < 2; ++c) {
            Ah[c] = *(const bf16x8*)&hhi[ab * HS + c * 32 + q * 8];
            Al[c] = *(const bf16x8*)&hlo[ab * HS + c * 32 + q * 8];
        }
        {
            const bf16x8 xvh = *(const bf16x8*)&xsp[ab * XS + s * 16];
            const bf16x8 xvl = *(const bf16x8*)&xsp[ab * XS + s * 16 + 8];
            const bf16x8 zf = {0, 0, 0, 0, 0, 0, 0, 0};
            Ah[2] = (q == 0) ? xvh : zf;
            Al[2] = (q == 0) ? xvl : zf;
        }

        // ---- MFMAs: z = (Ah+Al)(Bh+Bl), 3-term split ----
        f32x4 acc[5];
        #pragma unroll
        for (int t = 0; t < 5; ++t) {
            if (t < 4 || wave == 3) {
                f32x4 a = {0.0f, 0.0f, 0.0f, 0.0f};
                #pragma unroll
                for (int c = 0; c < 3; ++c) {
                    a = __builtin_amdgcn_mfma_f32_16x16x32_bf16(Al[c], Bh[t][c], a, 0, 0, 0);
                    a = __builtin_amdgcn_mfma_f32_16x16x32_bf16(Ah[c], Bl[t][c], a, 0, 0, 0);
                    a = __builtin_amdgcn_mfma_f32_16x16x32_bf16(Ah[c], Bh[t][c], a, 0, 0, 0);
                }
                acc[t] = a;
            }
        }

        // ---- write z to LDS (quads 0,1 hold batches 0..7) ----
        if (lane < 32) {
            #pragma unroll
            for (int t = 0; t < 4; ++t)
                *(f32x4*)&zbuf[(wave * 64 + t * 16 + n16) * 12 + q * 4] = acc[t];
            if (wave == 3 && n16 < FF)
                *(f32x4*)&frebuf[n16 * 12 + q * 4] = acc[4];
        }
        __syncthreads();

        // ---- pointwise: batch pb, hcols pc & pc+32 ----
        const float zi0 = zbuf[(0 * 64 + pc) * 12 + pb], zi1 = zbuf[(0 * 64 + pc + 32) * 12 + pb];
        const float zs0 = zbuf[(1 * 64 + pc) * 12 + pb], zs1 = zbuf[(1 * 64 + pc + 32) * 12 + pb];
        const float zc0 = zbuf[(2 * 64 + pc) * 12 + pb], zc1 = zbuf[(2 * 64 + pc + 32) * 12 + pb];
        const float zo0 = zbuf[(3 * 64 + pc) * 12 + pb], zo1 = zbuf[(3 * 64 + pc + 32) * 12 + pb];
        float fr[FF];
        #pragma unroll
        for (int f = 0; f < FF; ++f) fr[f] = hsig_f(frebuf[f * 12 + pb]);

        const float i0 = hsig_f(zi0), st0 = hsig_f(zs0), o0 = hsig_f(zo0);
        const float i1 = hsig_f(zi1), st1 = hsig_f(zs1), o1 = hsig_f(zo1);
        const float c0 = i0 * tanh_f(zc0);
        const float c1 = i1 * tanh_f(zc1);

        if (sm == 0) {
            #pragma unroll
            for (int f = 0; f < FF; ++f) { cs[f] = CBt[f]; sn[f] = SBt[f]; }
        }

        float a0 = ba0, a1 = ba1;
        #pragma unroll
        for (int f = 0; f < FF; ++f) {
            const float fc0 = st0 * fr[f], fc1 = st1 * fr[f];
            Sre0[f] = fmaf(fc0, Sre0[f], c0 * cs[f]);
            Sim0[f] = fmaf(fc0, Sim0[f], c0 * sn[f]);
            Sre1[f] = fmaf(fc1, Sre1[f], c1 * cs[f]);
            Sim1[f] = fmaf(fc1, Sim1[f], c1 * sn[f]);
            const float A0 = fmaf(Sim0[f], Sim0[f], Sre0[f] * Sre0[f]);
            const float A1 = fmaf(Sim1[f], Sim1[f], Sre1[f] * Sre1[f]);
            a0 = fmaf(A0, uav[f], a0);
            a1 = fmaf(A1, uav[f], a1);
            const float cc = cs[f];
            cs[f] = fmaf(cc, CBt[f], -(sn[f] * SBt[f]));
            sn[f] = fmaf(cc, SBt[f],   sn[f] * CBt[f]);
        }
        h0v = o0 * tanh_f(a0);
        h1v = o1 * tanh_f(a1);

        // split h -> bf16 hi/lo, write to LDS (the ONLY conversion point)
        {
            const unsigned short h0b = f2bf(h0v);
            const unsigned short h1b = f2bf(h1v);
            hhi[pb * HS + pc]      = h0b;
            hhi[pb * HS + pc + 32] = h1b;
            hlo[pb * HS + pc]      = f2bf(h0v - bf2f(h0b));
            hlo[pb * HS + pc + 32] = f2bf(h1v - bf2f(h1b));
        }
        if (++sm == 10) sm = 0;
        __syncthreads();
    }

    // ---- output: out[b] = sum_col h*W_p + b_p ----
    float val = fmaf(h0v, wp0, h1v * wp1);
    val += __shfl_xor(val, 8, 64);
    val += __shfl_xor(val, 16, 64);
    val += __shfl_xor(val, 32, 64);
    if ((lane >> 3) == 0) red[wave][pb] = val;   // lanes 0..7 hold the wave sum
    __syncthreads();
    if (tid < 8)
        out[b0 + tid] = red[0][tid] + red[1][tid] + red[2][tid] + red[3][tid] + bpv;
}

extern "C" void kernel_launch(void* const* d_in, const int* in_sizes, int n_in,
                              void* d_out, int out_size, void* d_ws, size_t ws_size,
                              hipStream_t stream) {
    (void)in_sizes; (void)n_in; (void)d_ws; (void)ws_size; (void)out_size;
    const float* x     = (const float*)d_in[0];
    const float* W_i   = (const float*)d_in[1];
    const float* U_i   = (const float*)d_in[2];
    const float* b_i   = (const float*)d_in[3];
    const float* W_ste = (const float*)d_in[4];
    const float* U_ste = (const float*)d_in[5];
    const float* b_ste = (const float*)d_in[6];
    const float* W_fre = (const float*)d_in[7];
    const float* U_fre = (const float*)d_in[8];
    const float* b_fre = (const float*)d_in[9];
    const float* W_c   = (const float*)d_in[10];
    const float* U_c   = (const float*)d_in[11];
    const float* b_c   = (const float*)d_in[12];
    const float* W_o   = (const float*)d_in[13];
    const float* U_o   = (const float*)d_in[14];
    const float* b_o   = (const float*)d_in[15];
    const float* U_a   = (const float*)d_in[16];
    const float* b_a   = (const float*)d_in[17];
    const float* W_p   = (const float*)d_in[18];
    const float* b_p   = (const float*)d_in[19];

    sfm_kernel<<<BB / 8, 256, 0, stream>>>(
        x, W_i, U_i, b_i, W_ste, U_ste, b_ste, W_fre, U_fre, b_fre,
        W_c, U_c, b_c, W_o, U_o, b_o, U_a, b_a, W_p, b_p, (float*)d_out);
}